// Round 16
// baseline (483.003 us; speedup 1.0000x reference)
//
#include <hip/hip_runtime.h>

#define NPTS   1048576
#define NLEV   16
#define TSIZE  (1u << 19)
#define HMASK  (TSIZE - 1u)
#define NBUCK  32768          // 32^3 Morton buckets

// floor(16 * b^l), b = 32^(1/15): f32-correct values
__device__ __constant__ float NLF_TAB[16] = {
    16.f, 20.f, 25.f, 32.f, 40.f, 50.f, 64.f, 80.f,
    101.f, 128.f, 161.f, 203.f, 256.f, 322.f, 406.f, 512.f};

__device__ __forceinline__ unsigned spread5(unsigned x) {
    x &= 0x1F;
    x = (x | (x << 8)) & 0x100F;
    x = (x | (x << 4)) & 0x10C3;
    x = (x | (x << 2)) & 0x1249;
    return x;
}

__device__ __forceinline__ unsigned morton_key(float u0, float u1, float u2) {
    unsigned k0 = min(31u, (unsigned)(u0 * 32.0f));
    unsigned k1 = min(31u, (unsigned)(u1 * 32.0f));
    unsigned k2 = min(31u, (unsigned)(u2 * 32.0f));
    return (spread5(k0) << 2) | (spread5(k1) << 1) | spread5(k2);
}

__device__ __forceinline__ void uvw(float x0, float x1, float x2,
                                    float* u0, float* u1, float* u2) {
    const float mn = -1.5f, mx = 1.5f, rng = 3.0f;
    *u0 = (fminf(fmaxf(x0, mn), mx) - mn) / rng;
    *u1 = (fminf(fmaxf(x1, mn), mx) - mn) / rng;
    *u2 = (fminf(fmaxf(x2, mn), mx) - mn) / rng;
}

__device__ __forceinline__ void level_lerp(
    float x0, float x1, float x2, float u0, float u1, float u2,
    float Nl, const float2* __restrict__ tab, float* r0, float* r1)
{
#pragma clang fp contract(off)
    const float mn = -1.5f, rng = 3.0f;
    const float box = rng / Nl;

    int g0 = (int)floorf(u0 * Nl);
    int g1 = (int)floorf(u1 * Nl);
    int g2 = (int)floorf(u2 * Nl);

    float vmin0 = (float)g0 * box + mn;
    float vmin1 = (float)g1 * box + mn;
    float vmin2 = (float)g2 * box + mn;

    float den0 = (vmin0 + box) - vmin0;
    float den1 = (vmin1 + box) - vmin1;
    float den2 = (vmin2 + box) - vmin2;

    float wx = (x0 - vmin0) / den0;
    float wy = (x1 - vmin1) / den1;
    float wz = (x2 - vmin2) / den2;

    unsigned hx0 = (unsigned)g0;
    unsigned hx1 = (unsigned)(g0 + 1);
    unsigned hy0 = (unsigned)g1       * 2654435761u;
    unsigned hy1 = (unsigned)(g1 + 1) * 2654435761u;
    unsigned hz0 = (unsigned)g2       * 805459861u;
    unsigned hz1 = (unsigned)(g2 + 1) * 805459861u;

    float2 e000 = tab[(hx0 ^ hy0 ^ hz0) & HMASK];
    float2 e001 = tab[(hx0 ^ hy0 ^ hz1) & HMASK];
    float2 e010 = tab[(hx0 ^ hy1 ^ hz0) & HMASK];
    float2 e011 = tab[(hx0 ^ hy1 ^ hz1) & HMASK];
    float2 e100 = tab[(hx1 ^ hy0 ^ hz0) & HMASK];
    float2 e101 = tab[(hx1 ^ hy0 ^ hz1) & HMASK];
    float2 e110 = tab[(hx1 ^ hy1 ^ hz0) & HMASK];
    float2 e111 = tab[(hx1 ^ hy1 ^ hz1) & HMASK];

    float omx = 1.0f - wx, omy = 1.0f - wy, omz = 1.0f - wz;
    {
        float c00 = e000.x * omx + e100.x * wx;
        float c01 = e001.x * omx + e101.x * wx;
        float c10 = e010.x * omx + e110.x * wx;
        float c11 = e011.x * omx + e111.x * wx;
        float c0  = c00 * omy + c10 * wy;
        float c1  = c01 * omy + c11 * wy;
        *r0 = c0 * omz + c1 * wz;
    }
    {
        float c00 = e000.y * omx + e100.y * wx;
        float c01 = e001.y * omx + e101.y * wx;
        float c10 = e010.y * omx + e110.y * wx;
        float c11 = e011.y * omx + e111.y * wx;
        float c0  = c00 * omy + c10 * wy;
        float c1  = c01 * omy + c11 * wy;
        *r1 = c0 * omz + c1 * wz;
    }
}

// Batched multi-level evaluate: NB levels starting at L0V. Computes all
// NB*8 indices, issues all loads, fences, then consumes. Amortizes gather
// latency across levels instead of one vmcnt(0) stall per level.
template<int L0V, int NB>
__device__ __forceinline__ void levels_batched(
    float x0, float x1, float x2, float u0, float u1, float u2,
    const float* __restrict__ tables, float* __restrict__ res)
{
#pragma clang fp contract(off)
    const float mn = -1.5f, rng = 3.0f;
    unsigned idx[NB * 8];
    float wxa[NB], wya[NB], wza[NB];

#pragma unroll
    for (int j = 0; j < NB; ++j) {
        const int l = L0V + j;
        const float Nl  = NLF_TAB[l];
        const float box = rng / Nl;

        int g0 = (int)floorf(u0 * Nl);
        int g1 = (int)floorf(u1 * Nl);
        int g2 = (int)floorf(u2 * Nl);

        float vmin0 = (float)g0 * box + mn;
        float vmin1 = (float)g1 * box + mn;
        float vmin2 = (float)g2 * box + mn;

        float den0 = (vmin0 + box) - vmin0;
        float den1 = (vmin1 + box) - vmin1;
        float den2 = (vmin2 + box) - vmin2;

        wxa[j] = (x0 - vmin0) / den0;
        wya[j] = (x1 - vmin1) / den1;
        wza[j] = (x2 - vmin2) / den2;

        unsigned hx0 = (unsigned)g0;
        unsigned hx1 = (unsigned)(g0 + 1);
        unsigned hy0 = (unsigned)g1       * 2654435761u;
        unsigned hy1 = (unsigned)(g1 + 1) * 2654435761u;
        unsigned hz0 = (unsigned)g2       * 805459861u;
        unsigned hz1 = (unsigned)(g2 + 1) * 805459861u;

        idx[j * 8 + 0] = (hx0 ^ hy0 ^ hz0) & HMASK;
        idx[j * 8 + 1] = (hx0 ^ hy0 ^ hz1) & HMASK;
        idx[j * 8 + 2] = (hx0 ^ hy1 ^ hz0) & HMASK;
        idx[j * 8 + 3] = (hx0 ^ hy1 ^ hz1) & HMASK;
        idx[j * 8 + 4] = (hx1 ^ hy0 ^ hz0) & HMASK;
        idx[j * 8 + 5] = (hx1 ^ hy0 ^ hz1) & HMASK;
        idx[j * 8 + 6] = (hx1 ^ hy1 ^ hz0) & HMASK;
        idx[j * 8 + 7] = (hx1 ^ hy1 ^ hz1) & HMASK;
    }

    float2 e[NB * 8];
#pragma unroll
    for (int j = 0; j < NB; ++j) {
        const float2* tab = (const float2*)tables + (size_t)(L0V + j) * TSIZE;
#pragma unroll
        for (int k = 0; k < 8; ++k)
            e[j * 8 + k] = tab[idx[j * 8 + k]];
    }
    asm volatile("" ::: "memory");   // keep loads hoisted above all consumes

#pragma unroll
    for (int j = 0; j < NB; ++j) {
        float wx = wxa[j], wy = wya[j], wz = wza[j];
        float omx = 1.0f - wx, omy = 1.0f - wy, omz = 1.0f - wz;
        const float2* ee = &e[j * 8];
        {
            float c00 = ee[0].x * omx + ee[4].x * wx;
            float c01 = ee[1].x * omx + ee[5].x * wx;
            float c10 = ee[2].x * omx + ee[6].x * wx;
            float c11 = ee[3].x * omx + ee[7].x * wx;
            float c0  = c00 * omy + c10 * wy;
            float c1  = c01 * omy + c11 * wy;
            res[2 * (L0V + j) + 0] = c0 * omz + c1 * wz;
        }
        {
            float c00 = ee[0].y * omx + ee[4].y * wx;
            float c01 = ee[1].y * omx + ee[5].y * wx;
            float c10 = ee[2].y * omx + ee[6].y * wx;
            float c11 = ee[3].y * omx + ee[7].y * wx;
            float c0  = c00 * omy + c10 * wy;
            float c1  = c01 * omy + c11 * wy;
            res[2 * (L0V + j) + 1] = c0 * omz + c1 * wz;
        }
    }
}

// ---------- fine-level body ----------

template<int L, bool DO_HIST, bool DO_MASK>
__device__ __forceinline__ void fine_body(
    const float* __restrict__ xin, const float* __restrict__ tables,
    float* __restrict__ out, unsigned* __restrict__ hist, int p)
{
#pragma clang fp contract(off)
    float x0 = __builtin_nontemporal_load(&xin[3 * p + 0]);
    float x1 = __builtin_nontemporal_load(&xin[3 * p + 1]);
    float x2 = __builtin_nontemporal_load(&xin[3 * p + 2]);
    float u0, u1, u2; uvw(x0, x1, x2, &u0, &u1, &u2);

    if (DO_HIST)
        atomicAdd(&hist[morton_key(u0, u1, u2)], 1u);

    const float2* tab = (const float2*)tables + (size_t)L * TSIZE;
    float r0, r1;
    level_lerp(x0, x1, x2, u0, u1, u2, NLF_TAB[L], tab, &r0, &r1);
    *(float2*)(out + (size_t)p * 32 + 2 * L) = make_float2(r0, r1);

    if (DO_MASK) {
        const float mn = -1.5f, mx = 1.5f;
        float keep = (x0 >= mn && x0 <= mx &&
                      x1 >= mn && x1 <= mx &&
                      x2 >= mn && x2 <= mx) ? 1.0f : 0.0f;
        out[(size_t)NPTS * 32 + p] = keep;
    }
}

template<int L, bool DO_HIST, bool DO_MASK>
__global__ __launch_bounds__(256)
void fine_kernel(const float* __restrict__ xin,
                 const float* __restrict__ tables,
                 float* __restrict__ out,
                 unsigned* __restrict__ hist)
{
    int p = blockIdx.x * 256 + threadIdx.x;
    if (p >= NPTS) return;
    fine_body<L, DO_HIST, DO_MASK>(xin, tables, out, hist, p);
}

// fine14 + scan: blocks 0..4095 do L14; block 4096 scans the (complete)
// histogram into cursors in-place.
__global__ __launch_bounds__(256)
void fine14_scan(const float* __restrict__ xin,
                 const float* __restrict__ tables,
                 float* __restrict__ out,
                 unsigned* __restrict__ hist)
{
    __shared__ unsigned part[256];
    if (blockIdx.x < 4096) {
        int p = blockIdx.x * 256 + threadIdx.x;
        fine_body<14, false, false>(xin, tables, out, hist, p);
        return;
    }
    int t = threadIdx.x;
    unsigned s = 0;
    for (int i = 0; i < 128; ++i) s += hist[t * 128 + i];
    part[t] = s;
    __syncthreads();
    for (int off = 1; off < 256; off <<= 1) {
        unsigned v = (t >= off) ? part[t - off] : 0;
        __syncthreads();
        part[t] += v;
        __syncthreads();
    }
    unsigned base = (t == 0) ? 0u : part[t - 1];
    for (int i = 0; i < 128; ++i) {
        unsigned c = hist[t * 128 + i];
        hist[t * 128 + i] = base;     // cursor
        base += c;
    }
}

// ---------- sort kernels ----------

// Scatter: p packed into sx4.w (bitcast) - no separate sidx buffer.
__global__ __launch_bounds__(256)
void scatter_kernel(const float* __restrict__ xin,
                    unsigned* __restrict__ cursor,
                    float4* __restrict__ sx4)
{
    int p = blockIdx.x * 256 + threadIdx.x;
    if (p >= NPTS) return;
    float x0 = __builtin_nontemporal_load(&xin[3 * p + 0]);
    float x1 = __builtin_nontemporal_load(&xin[3 * p + 1]);
    float x2 = __builtin_nontemporal_load(&xin[3 * p + 2]);
    float u0, u1, u2; uvw(x0, x1, x2, &u0, &u1, &u2);
    unsigned pos = atomicAdd(&cursor[morton_key(u0, u1, u2)], 1u);
    sx4[pos] = make_float4(x0, x1, x2, __uint_as_float((unsigned)p));
}

// ---------- sorted compute kernels ----------

// Levels 0..7 over sorted points, 2x4-level load batches.
__global__ __launch_bounds__(256)
void coarse_sorted(const float4* __restrict__ sx4,
                   const float* __restrict__ tables,
                   float* __restrict__ out)
{
#pragma clang fp contract(off)
    int s = blockIdx.x * 256 + threadIdx.x;
    if (s >= NPTS) return;
    float4 xv = sx4[s];
    unsigned p = __float_as_uint(xv.w);
    float u0, u1, u2; uvw(xv.x, xv.y, xv.z, &u0, &u1, &u2);

    float res[16];
    levels_batched<0, 4>(xv.x, xv.y, xv.z, u0, u1, u2, tables, res);
    levels_batched<4, 4>(xv.x, xv.y, xv.z, u0, u1, u2, tables, res);

    float4* orow = (float4*)(out + (size_t)p * 32);
#pragma unroll
    for (int i = 0; i < 4; ++i)
        orow[i] = make_float4(res[4 * i + 0], res[4 * i + 1],
                              res[4 * i + 2], res[4 * i + 3]);
}

// Levels 8,9 over sorted points, one 2-level load batch.
__global__ __launch_bounds__(256)
void mid_sorted(const float4* __restrict__ sx4,
                const float* __restrict__ tables,
                float* __restrict__ out)
{
#pragma clang fp contract(off)
    int s = blockIdx.x * 256 + threadIdx.x;
    if (s >= NPTS) return;
    float4 xv = sx4[s];
    unsigned p = __float_as_uint(xv.w);
    float u0, u1, u2; uvw(xv.x, xv.y, xv.z, &u0, &u1, &u2);

    float res[20];
    levels_batched<8, 2>(xv.x, xv.y, xv.z, u0, u1, u2, tables, res);

    *(float4*)(out + (size_t)p * 32 + 16) =
        make_float4(res[16], res[17], res[18], res[19]);
}

// ---------- fallback (no-workspace path) ----------

__global__ __launch_bounds__(256)
void coarse_kernel(const float* __restrict__ xin,
                   const float* __restrict__ tables,
                   float* __restrict__ out)
{
#pragma clang fp contract(off)
    int p = blockIdx.x * 256 + threadIdx.x;
    if (p >= NPTS) return;
    float x0 = xin[3 * p], x1 = xin[3 * p + 1], x2 = xin[3 * p + 2];
    float u0, u1, u2; uvw(x0, x1, x2, &u0, &u1, &u2);

    float res[16];
#pragma unroll
    for (int l = 0; l < 8; ++l) {
        const float2* tab = (const float2*)tables + (size_t)l * TSIZE;
        level_lerp(x0, x1, x2, u0, u1, u2, NLF_TAB[l], tab,
                   &res[2 * l], &res[2 * l + 1]);
    }
    float4* orow = (float4*)(out + (size_t)p * 32);
#pragma unroll
    for (int i = 0; i < 4; ++i)
        orow[i] = make_float4(res[4 * i + 0], res[4 * i + 1],
                              res[4 * i + 2], res[4 * i + 3]);
}

extern "C" void kernel_launch(void* const* d_in, const int* in_sizes, int n_in,
                              void* d_out, int out_size, void* d_ws, size_t ws_size,
                              hipStream_t stream) {
    const float* x      = (const float*)d_in[0];
    const float* tables = (const float*)d_in[2];
    float* out = (float*)d_out;

    int n = in_sizes[0] / 3;           // 1048576
    int blocks = (n + 255) / 256;      // 4096

    const size_t HIST_B  = (size_t)NBUCK * 4;               // 128 KB
    const size_t SX4_OFF = 131072;                          // aligned
    const size_t NEEDED  = SX4_OFF + (size_t)NPTS * 16;     // ≈ 16.9 MB

    if (ws_size >= NEEDED) {
        unsigned* hist = (unsigned*)d_ws;
        float4*   sx4  = (float4*)((char*)d_ws + SX4_OFF);

        hipMemsetAsync(hist, 0, HIST_B, stream);

        // One table L2-resident per launch; hist/scan ride along for free.
        fine_kernel<15, true , false><<<blocks, 256, 0, stream>>>(x, tables, out, hist);
        fine14_scan<<<blocks + 1, 256, 0, stream>>>(x, tables, out, hist);
        fine_kernel<13, false, false><<<blocks, 256, 0, stream>>>(x, tables, out, hist);
        fine_kernel<12, false, false><<<blocks, 256, 0, stream>>>(x, tables, out, hist);
        fine_kernel<11, false, false><<<blocks, 256, 0, stream>>>(x, tables, out, hist);
        fine_kernel<10, false, true ><<<blocks, 256, 0, stream>>>(x, tables, out, hist);

        scatter_kernel<<<blocks, 256, 0, stream>>>(x, hist, sx4);
        coarse_sorted<<<blocks, 256, 0, stream>>>(sx4, tables, out);
        mid_sorted<<<blocks, 256, 0, stream>>>(sx4, tables, out);
    } else {
        coarse_kernel<<<blocks, 256, 0, stream>>>(x, tables, out);
        fine_kernel< 8, false, false><<<blocks, 256, 0, stream>>>(x, tables, out, nullptr);
        fine_kernel< 9, false, false><<<blocks, 256, 0, stream>>>(x, tables, out, nullptr);
        fine_kernel<10, false, true ><<<blocks, 256, 0, stream>>>(x, tables, out, nullptr);
        fine_kernel<11, false, false><<<blocks, 256, 0, stream>>>(x, tables, out, nullptr);
        fine_kernel<12, false, false><<<blocks, 256, 0, stream>>>(x, tables, out, nullptr);
        fine_kernel<13, false, false><<<blocks, 256, 0, stream>>>(x, tables, out, nullptr);
        fine_kernel<14, false, false><<<blocks, 256, 0, stream>>>(x, tables, out, nullptr);
        fine_kernel<15, false, false><<<blocks, 256, 0, stream>>>(x, tables, out, nullptr);
    }
}

// Round 17
// 450.172 us; speedup vs baseline: 1.0729x; 1.0729x over previous
//
#include <hip/hip_runtime.h>

#define NPTS   1048576
#define NLEV   16
#define TSIZE  (1u << 19)
#define HMASK  (TSIZE - 1u)
#define NBUCK  32768          // 32^3 Morton buckets

// floor(16 * b^l), b = 32^(1/15): f32-correct values
__device__ __constant__ float NLF_TAB[16] = {
    16.f, 20.f, 25.f, 32.f, 40.f, 50.f, 64.f, 80.f,
    101.f, 128.f, 161.f, 203.f, 256.f, 322.f, 406.f, 512.f};

__device__ __forceinline__ unsigned spread5(unsigned x) {
    x &= 0x1F;
    x = (x | (x << 8)) & 0x100F;
    x = (x | (x << 4)) & 0x10C3;
    x = (x | (x << 2)) & 0x1249;
    return x;
}

__device__ __forceinline__ unsigned morton_key(float u0, float u1, float u2) {
    unsigned k0 = min(31u, (unsigned)(u0 * 32.0f));
    unsigned k1 = min(31u, (unsigned)(u1 * 32.0f));
    unsigned k2 = min(31u, (unsigned)(u2 * 32.0f));
    return (spread5(k0) << 2) | (spread5(k1) << 1) | spread5(k2);
}

__device__ __forceinline__ void uvw(float x0, float x1, float x2,
                                    float* u0, float* u1, float* u2) {
    const float mn = -1.5f, mx = 1.5f, rng = 3.0f;
    *u0 = (fminf(fmaxf(x0, mn), mx) - mn) / rng;
    *u1 = (fminf(fmaxf(x1, mn), mx) - mn) / rng;
    *u2 = (fminf(fmaxf(x2, mn), mx) - mn) / rng;
}

__device__ __forceinline__ void level_lerp(
    float x0, float x1, float x2, float u0, float u1, float u2,
    float Nl, const float2* __restrict__ tab, float* r0, float* r1)
{
#pragma clang fp contract(off)
    const float mn = -1.5f, rng = 3.0f;
    const float box = rng / Nl;

    int g0 = (int)floorf(u0 * Nl);
    int g1 = (int)floorf(u1 * Nl);
    int g2 = (int)floorf(u2 * Nl);

    float vmin0 = (float)g0 * box + mn;
    float vmin1 = (float)g1 * box + mn;
    float vmin2 = (float)g2 * box + mn;

    float den0 = (vmin0 + box) - vmin0;
    float den1 = (vmin1 + box) - vmin1;
    float den2 = (vmin2 + box) - vmin2;

    float wx = (x0 - vmin0) / den0;
    float wy = (x1 - vmin1) / den1;
    float wz = (x2 - vmin2) / den2;

    unsigned hx0 = (unsigned)g0;
    unsigned hx1 = (unsigned)(g0 + 1);
    unsigned hy0 = (unsigned)g1       * 2654435761u;
    unsigned hy1 = (unsigned)(g1 + 1) * 2654435761u;
    unsigned hz0 = (unsigned)g2       * 805459861u;
    unsigned hz1 = (unsigned)(g2 + 1) * 805459861u;

    float2 e000 = tab[(hx0 ^ hy0 ^ hz0) & HMASK];
    float2 e001 = tab[(hx0 ^ hy0 ^ hz1) & HMASK];
    float2 e010 = tab[(hx0 ^ hy1 ^ hz0) & HMASK];
    float2 e011 = tab[(hx0 ^ hy1 ^ hz1) & HMASK];
    float2 e100 = tab[(hx1 ^ hy0 ^ hz0) & HMASK];
    float2 e101 = tab[(hx1 ^ hy0 ^ hz1) & HMASK];
    float2 e110 = tab[(hx1 ^ hy1 ^ hz0) & HMASK];
    float2 e111 = tab[(hx1 ^ hy1 ^ hz1) & HMASK];

    float omx = 1.0f - wx, omy = 1.0f - wy, omz = 1.0f - wz;
    {
        float c00 = e000.x * omx + e100.x * wx;
        float c01 = e001.x * omx + e101.x * wx;
        float c10 = e010.x * omx + e110.x * wx;
        float c11 = e011.x * omx + e111.x * wx;
        float c0  = c00 * omy + c10 * wy;
        float c1  = c01 * omy + c11 * wy;
        *r0 = c0 * omz + c1 * wz;
    }
    {
        float c00 = e000.y * omx + e100.y * wx;
        float c01 = e001.y * omx + e101.y * wx;
        float c10 = e010.y * omx + e110.y * wx;
        float c11 = e011.y * omx + e111.y * wx;
        float c0  = c00 * omy + c10 * wy;
        float c1  = c01 * omy + c11 * wy;
        *r1 = c0 * omz + c1 * wz;
    }
}

// Batched multi-level evaluate: NB levels starting at L0V. Computes all
// NB*8 indices, issues all loads, fences, then consumes.
template<int L0V, int NB>
__device__ __forceinline__ void levels_batched(
    float x0, float x1, float x2, float u0, float u1, float u2,
    const float* __restrict__ tables, float* __restrict__ res)
{
#pragma clang fp contract(off)
    const float mn = -1.5f, rng = 3.0f;
    unsigned idx[NB * 8];
    float wxa[NB], wya[NB], wza[NB];

#pragma unroll
    for (int j = 0; j < NB; ++j) {
        const int l = L0V + j;
        const float Nl  = NLF_TAB[l];
        const float box = rng / Nl;

        int g0 = (int)floorf(u0 * Nl);
        int g1 = (int)floorf(u1 * Nl);
        int g2 = (int)floorf(u2 * Nl);

        float vmin0 = (float)g0 * box + mn;
        float vmin1 = (float)g1 * box + mn;
        float vmin2 = (float)g2 * box + mn;

        float den0 = (vmin0 + box) - vmin0;
        float den1 = (vmin1 + box) - vmin1;
        float den2 = (vmin2 + box) - vmin2;

        wxa[j] = (x0 - vmin0) / den0;
        wya[j] = (x1 - vmin1) / den1;
        wza[j] = (x2 - vmin2) / den2;

        unsigned hx0 = (unsigned)g0;
        unsigned hx1 = (unsigned)(g0 + 1);
        unsigned hy0 = (unsigned)g1       * 2654435761u;
        unsigned hy1 = (unsigned)(g1 + 1) * 2654435761u;
        unsigned hz0 = (unsigned)g2       * 805459861u;
        unsigned hz1 = (unsigned)(g2 + 1) * 805459861u;

        idx[j * 8 + 0] = (hx0 ^ hy0 ^ hz0) & HMASK;
        idx[j * 8 + 1] = (hx0 ^ hy0 ^ hz1) & HMASK;
        idx[j * 8 + 2] = (hx0 ^ hy1 ^ hz0) & HMASK;
        idx[j * 8 + 3] = (hx0 ^ hy1 ^ hz1) & HMASK;
        idx[j * 8 + 4] = (hx1 ^ hy0 ^ hz0) & HMASK;
        idx[j * 8 + 5] = (hx1 ^ hy0 ^ hz1) & HMASK;
        idx[j * 8 + 6] = (hx1 ^ hy1 ^ hz0) & HMASK;
        idx[j * 8 + 7] = (hx1 ^ hy1 ^ hz1) & HMASK;
    }

    float2 e[NB * 8];
#pragma unroll
    for (int j = 0; j < NB; ++j) {
        const float2* tab = (const float2*)tables + (size_t)(L0V + j) * TSIZE;
#pragma unroll
        for (int k = 0; k < 8; ++k)
            e[j * 8 + k] = tab[idx[j * 8 + k]];
    }
    asm volatile("" ::: "memory");   // keep loads hoisted above all consumes

#pragma unroll
    for (int j = 0; j < NB; ++j) {
        float wx = wxa[j], wy = wya[j], wz = wza[j];
        float omx = 1.0f - wx, omy = 1.0f - wy, omz = 1.0f - wz;
        const float2* ee = &e[j * 8];
        {
            float c00 = ee[0].x * omx + ee[4].x * wx;
            float c01 = ee[1].x * omx + ee[5].x * wx;
            float c10 = ee[2].x * omx + ee[6].x * wx;
            float c11 = ee[3].x * omx + ee[7].x * wx;
            float c0  = c00 * omy + c10 * wy;
            float c1  = c01 * omy + c11 * wy;
            res[2 * (L0V + j) + 0] = c0 * omz + c1 * wz;
        }
        {
            float c00 = ee[0].y * omx + ee[4].y * wx;
            float c01 = ee[1].y * omx + ee[5].y * wx;
            float c10 = ee[2].y * omx + ee[6].y * wx;
            float c11 = ee[3].y * omx + ee[7].y * wx;
            float c0  = c00 * omy + c10 * wy;
            float c1  = c01 * omy + c11 * wy;
            res[2 * (L0V + j) + 1] = c0 * omz + c1 * wz;
        }
    }
}

// ---------- fine-level body ----------

template<int L, bool DO_HIST, bool DO_MASK>
__device__ __forceinline__ void fine_body(
    const float* __restrict__ xin, const float* __restrict__ tables,
    float* __restrict__ out, unsigned* __restrict__ hist, int p)
{
#pragma clang fp contract(off)
    float x0 = xin[3 * p], x1 = xin[3 * p + 1], x2 = xin[3 * p + 2];
    float u0, u1, u2; uvw(x0, x1, x2, &u0, &u1, &u2);

    if (DO_HIST)
        atomicAdd(&hist[morton_key(u0, u1, u2)], 1u);

    const float2* tab = (const float2*)tables + (size_t)L * TSIZE;
    float r0, r1;
    level_lerp(x0, x1, x2, u0, u1, u2, NLF_TAB[L], tab, &r0, &r1);
    *(float2*)(out + (size_t)p * 32 + 2 * L) = make_float2(r0, r1);

    if (DO_MASK) {
        const float mn = -1.5f, mx = 1.5f;
        float keep = (x0 >= mn && x0 <= mx &&
                      x1 >= mn && x1 <= mx &&
                      x2 >= mn && x2 <= mx) ? 1.0f : 0.0f;
        out[(size_t)NPTS * 32 + p] = keep;
    }
}

template<int L, bool DO_HIST, bool DO_MASK>
__global__ __launch_bounds__(256)
void fine_kernel(const float* __restrict__ xin,
                 const float* __restrict__ tables,
                 float* __restrict__ out,
                 unsigned* __restrict__ hist)
{
    int p = blockIdx.x * 256 + threadIdx.x;
    if (p >= NPTS) return;
    fine_body<L, DO_HIST, DO_MASK>(xin, tables, out, hist, p);
}

// fine14 + scan: blocks 0..4095 do L14; block 4096 scans the (complete)
// histogram into cursors in-place.
__global__ __launch_bounds__(256)
void fine14_scan(const float* __restrict__ xin,
                 const float* __restrict__ tables,
                 float* __restrict__ out,
                 unsigned* __restrict__ hist)
{
    __shared__ unsigned part[256];
    if (blockIdx.x < 4096) {
        int p = blockIdx.x * 256 + threadIdx.x;
        fine_body<14, false, false>(xin, tables, out, hist, p);
        return;
    }
    int t = threadIdx.x;
    unsigned s = 0;
    for (int i = 0; i < 128; ++i) s += hist[t * 128 + i];
    part[t] = s;
    __syncthreads();
    for (int off = 1; off < 256; off <<= 1) {
        unsigned v = (t >= off) ? part[t - off] : 0;
        __syncthreads();
        part[t] += v;
        __syncthreads();
    }
    unsigned base = (t == 0) ? 0u : part[t - 1];
    for (int i = 0; i < 128; ++i) {
        unsigned c = hist[t * 128 + i];
        hist[t * 128 + i] = base;     // cursor
        base += c;
    }
}

// ---------- sort kernels ----------

// Scatter: p packed into sx4.w (bitcast) - no separate sidx buffer.
__global__ __launch_bounds__(256)
void scatter_kernel(const float* __restrict__ xin,
                    unsigned* __restrict__ cursor,
                    float4* __restrict__ sx4)
{
    int p = blockIdx.x * 256 + threadIdx.x;
    if (p >= NPTS) return;
    float x0 = xin[3 * p], x1 = xin[3 * p + 1], x2 = xin[3 * p + 2];
    float u0, u1, u2; uvw(x0, x1, x2, &u0, &u1, &u2);
    unsigned pos = atomicAdd(&cursor[morton_key(u0, u1, u2)], 1u);
    sx4[pos] = make_float4(x0, x1, x2, __uint_as_float((unsigned)p));
}

// ---------- sorted compute kernels ----------

// Levels 0..7 over sorted points, 2x4-level load batches.
__global__ __launch_bounds__(256)
void coarse_sorted(const float4* __restrict__ sx4,
                   const float* __restrict__ tables,
                   float* __restrict__ out)
{
#pragma clang fp contract(off)
    int s = blockIdx.x * 256 + threadIdx.x;
    if (s >= NPTS) return;
    float4 xv = sx4[s];
    unsigned p = __float_as_uint(xv.w);
    float u0, u1, u2; uvw(xv.x, xv.y, xv.z, &u0, &u1, &u2);

    float res[16];
    levels_batched<0, 4>(xv.x, xv.y, xv.z, u0, u1, u2, tables, res);
    levels_batched<4, 4>(xv.x, xv.y, xv.z, u0, u1, u2, tables, res);

    float4* orow = (float4*)(out + (size_t)p * 32);
#pragma unroll
    for (int i = 0; i < 4; ++i)
        orow[i] = make_float4(res[4 * i + 0], res[4 * i + 1],
                              res[4 * i + 2], res[4 * i + 3]);
}

// Levels 8,9 over sorted points, one 2-level load batch.
__global__ __launch_bounds__(256)
void mid_sorted(const float4* __restrict__ sx4,
                const float* __restrict__ tables,
                float* __restrict__ out)
{
#pragma clang fp contract(off)
    int s = blockIdx.x * 256 + threadIdx.x;
    if (s >= NPTS) return;
    float4 xv = sx4[s];
    unsigned p = __float_as_uint(xv.w);
    float u0, u1, u2; uvw(xv.x, xv.y, xv.z, &u0, &u1, &u2);

    float res[20];
    levels_batched<8, 2>(xv.x, xv.y, xv.z, u0, u1, u2, tables, res);

    *(float4*)(out + (size_t)p * 32 + 16) =
        make_float4(res[16], res[17], res[18], res[19]);
}

// ---------- fallback (no-workspace path) ----------

__global__ __launch_bounds__(256)
void coarse_kernel(const float* __restrict__ xin,
                   const float* __restrict__ tables,
                   float* __restrict__ out)
{
#pragma clang fp contract(off)
    int p = blockIdx.x * 256 + threadIdx.x;
    if (p >= NPTS) return;
    float x0 = xin[3 * p], x1 = xin[3 * p + 1], x2 = xin[3 * p + 2];
    float u0, u1, u2; uvw(x0, x1, x2, &u0, &u1, &u2);

    float res[16];
#pragma unroll
    for (int l = 0; l < 8; ++l) {
        const float2* tab = (const float2*)tables + (size_t)l * TSIZE;
        level_lerp(x0, x1, x2, u0, u1, u2, NLF_TAB[l], tab,
                   &res[2 * l], &res[2 * l + 1]);
    }
    float4* orow = (float4*)(out + (size_t)p * 32);
#pragma unroll
    for (int i = 0; i < 4; ++i)
        orow[i] = make_float4(res[4 * i + 0], res[4 * i + 1],
                              res[4 * i + 2], res[4 * i + 3]);
}

extern "C" void kernel_launch(void* const* d_in, const int* in_sizes, int n_in,
                              void* d_out, int out_size, void* d_ws, size_t ws_size,
                              hipStream_t stream) {
    const float* x      = (const float*)d_in[0];
    const float* tables = (const float*)d_in[2];
    float* out = (float*)d_out;

    int n = in_sizes[0] / 3;           // 1048576
    int blocks = (n + 255) / 256;      // 4096

    const size_t HIST_B  = (size_t)NBUCK * 4;               // 128 KB
    const size_t SX4_OFF = 131072;                          // aligned
    const size_t NEEDED  = SX4_OFF + (size_t)NPTS * 16;     // ≈ 16.9 MB

    if (ws_size >= NEEDED) {
        unsigned* hist = (unsigned*)d_ws;
        float4*   sx4  = (float4*)((char*)d_ws + SX4_OFF);

        hipMemsetAsync(hist, 0, HIST_B, stream);

        // One table L2-resident per launch; hist/scan ride along for free.
        fine_kernel<15, true , false><<<blocks, 256, 0, stream>>>(x, tables, out, hist);
        fine14_scan<<<blocks + 1, 256, 0, stream>>>(x, tables, out, hist);
        fine_kernel<13, false, false><<<blocks, 256, 0, stream>>>(x, tables, out, hist);
        fine_kernel<12, false, false><<<blocks, 256, 0, stream>>>(x, tables, out, hist);
        fine_kernel<11, false, false><<<blocks, 256, 0, stream>>>(x, tables, out, hist);
        fine_kernel<10, false, true ><<<blocks, 256, 0, stream>>>(x, tables, out, hist);

        scatter_kernel<<<blocks, 256, 0, stream>>>(x, hist, sx4);
        coarse_sorted<<<blocks, 256, 0, stream>>>(sx4, tables, out);
        mid_sorted<<<blocks, 256, 0, stream>>>(sx4, tables, out);
    } else {
        coarse_kernel<<<blocks, 256, 0, stream>>>(x, tables, out);
        fine_kernel< 8, false, false><<<blocks, 256, 0, stream>>>(x, tables, out, nullptr);
        fine_kernel< 9, false, false><<<blocks, 256, 0, stream>>>(x, tables, out, nullptr);
        fine_kernel<10, false, true ><<<blocks, 256, 0, stream>>>(x, tables, out, nullptr);
        fine_kernel<11, false, false><<<blocks, 256, 0, stream>>>(x, tables, out, nullptr);
        fine_kernel<12, false, false><<<blocks, 256, 0, stream>>>(x, tables, out, nullptr);
        fine_kernel<13, false, false><<<blocks, 256, 0, stream>>>(x, tables, out, nullptr);
        fine_kernel<14, false, false><<<blocks, 256, 0, stream>>>(x, tables, out, nullptr);
        fine_kernel<15, false, false><<<blocks, 256, 0, stream>>>(x, tables, out, nullptr);
    }
}

// Round 18
// 441.968 us; speedup vs baseline: 1.0928x; 1.0186x over previous
//
#include <hip/hip_runtime.h>

#define NPTS   1048576
#define NLEV   16
#define TSIZE  (1u << 19)
#define HMASK  (TSIZE - 1u)
#define NBUCK  32768          // 32^3 Morton buckets

// floor(16 * b^l), b = 32^(1/15): f32-correct values
__device__ __constant__ float NLF_TAB[16] = {
    16.f, 20.f, 25.f, 32.f, 40.f, 50.f, 64.f, 80.f,
    101.f, 128.f, 161.f, 203.f, 256.f, 322.f, 406.f, 512.f};

__device__ __forceinline__ unsigned spread5(unsigned x) {
    x &= 0x1F;
    x = (x | (x << 8)) & 0x100F;
    x = (x | (x << 4)) & 0x10C3;
    x = (x | (x << 2)) & 0x1249;
    return x;
}

__device__ __forceinline__ unsigned morton_key(float u0, float u1, float u2) {
    unsigned k0 = min(31u, (unsigned)(u0 * 32.0f));
    unsigned k1 = min(31u, (unsigned)(u1 * 32.0f));
    unsigned k2 = min(31u, (unsigned)(u2 * 32.0f));
    return (spread5(k0) << 2) | (spread5(k1) << 1) | spread5(k2);
}

__device__ __forceinline__ void uvw(float x0, float x1, float x2,
                                    float* u0, float* u1, float* u2) {
    const float mn = -1.5f, mx = 1.5f, rng = 3.0f;
    *u0 = (fminf(fmaxf(x0, mn), mx) - mn) / rng;
    *u1 = (fminf(fmaxf(x1, mn), mx) - mn) / rng;
    *u2 = (fminf(fmaxf(x2, mn), mx) - mn) / rng;
}

__device__ __forceinline__ void level_lerp(
    float x0, float x1, float x2, float u0, float u1, float u2,
    float Nl, const float2* __restrict__ tab, float* r0, float* r1)
{
#pragma clang fp contract(off)
    const float mn = -1.5f, rng = 3.0f;
    const float box = rng / Nl;

    int g0 = (int)floorf(u0 * Nl);
    int g1 = (int)floorf(u1 * Nl);
    int g2 = (int)floorf(u2 * Nl);

    float vmin0 = (float)g0 * box + mn;
    float vmin1 = (float)g1 * box + mn;
    float vmin2 = (float)g2 * box + mn;

    float den0 = (vmin0 + box) - vmin0;
    float den1 = (vmin1 + box) - vmin1;
    float den2 = (vmin2 + box) - vmin2;

    float wx = (x0 - vmin0) / den0;
    float wy = (x1 - vmin1) / den1;
    float wz = (x2 - vmin2) / den2;

    unsigned hx0 = (unsigned)g0;
    unsigned hx1 = (unsigned)(g0 + 1);
    unsigned hy0 = (unsigned)g1       * 2654435761u;
    unsigned hy1 = (unsigned)(g1 + 1) * 2654435761u;
    unsigned hz0 = (unsigned)g2       * 805459861u;
    unsigned hz1 = (unsigned)(g2 + 1) * 805459861u;

    float2 e000 = tab[(hx0 ^ hy0 ^ hz0) & HMASK];
    float2 e001 = tab[(hx0 ^ hy0 ^ hz1) & HMASK];
    float2 e010 = tab[(hx0 ^ hy1 ^ hz0) & HMASK];
    float2 e011 = tab[(hx0 ^ hy1 ^ hz1) & HMASK];
    float2 e100 = tab[(hx1 ^ hy0 ^ hz0) & HMASK];
    float2 e101 = tab[(hx1 ^ hy0 ^ hz1) & HMASK];
    float2 e110 = tab[(hx1 ^ hy1 ^ hz0) & HMASK];
    float2 e111 = tab[(hx1 ^ hy1 ^ hz1) & HMASK];

    float omx = 1.0f - wx, omy = 1.0f - wy, omz = 1.0f - wz;
    {
        float c00 = e000.x * omx + e100.x * wx;
        float c01 = e001.x * omx + e101.x * wx;
        float c10 = e010.x * omx + e110.x * wx;
        float c11 = e011.x * omx + e111.x * wx;
        float c0  = c00 * omy + c10 * wy;
        float c1  = c01 * omy + c11 * wy;
        *r0 = c0 * omz + c1 * wz;
    }
    {
        float c00 = e000.y * omx + e100.y * wx;
        float c01 = e001.y * omx + e101.y * wx;
        float c10 = e010.y * omx + e110.y * wx;
        float c11 = e011.y * omx + e111.y * wx;
        float c0  = c00 * omy + c10 * wy;
        float c1  = c01 * omy + c11 * wy;
        *r1 = c0 * omz + c1 * wz;
    }
}

// Batched multi-level evaluate: NB levels starting at L0V. Computes all
// NB*8 indices, issues all loads, fences, then consumes.
template<int L0V, int NB>
__device__ __forceinline__ void levels_batched(
    float x0, float x1, float x2, float u0, float u1, float u2,
    const float* __restrict__ tables, float* __restrict__ res)
{
#pragma clang fp contract(off)
    const float mn = -1.5f, rng = 3.0f;
    unsigned idx[NB * 8];
    float wxa[NB], wya[NB], wza[NB];

#pragma unroll
    for (int j = 0; j < NB; ++j) {
        const int l = L0V + j;
        const float Nl  = NLF_TAB[l];
        const float box = rng / Nl;

        int g0 = (int)floorf(u0 * Nl);
        int g1 = (int)floorf(u1 * Nl);
        int g2 = (int)floorf(u2 * Nl);

        float vmin0 = (float)g0 * box + mn;
        float vmin1 = (float)g1 * box + mn;
        float vmin2 = (float)g2 * box + mn;

        float den0 = (vmin0 + box) - vmin0;
        float den1 = (vmin1 + box) - vmin1;
        float den2 = (vmin2 + box) - vmin2;

        wxa[j] = (x0 - vmin0) / den0;
        wya[j] = (x1 - vmin1) / den1;
        wza[j] = (x2 - vmin2) / den2;

        unsigned hx0 = (unsigned)g0;
        unsigned hx1 = (unsigned)(g0 + 1);
        unsigned hy0 = (unsigned)g1       * 2654435761u;
        unsigned hy1 = (unsigned)(g1 + 1) * 2654435761u;
        unsigned hz0 = (unsigned)g2       * 805459861u;
        unsigned hz1 = (unsigned)(g2 + 1) * 805459861u;

        idx[j * 8 + 0] = (hx0 ^ hy0 ^ hz0) & HMASK;
        idx[j * 8 + 1] = (hx0 ^ hy0 ^ hz1) & HMASK;
        idx[j * 8 + 2] = (hx0 ^ hy1 ^ hz0) & HMASK;
        idx[j * 8 + 3] = (hx0 ^ hy1 ^ hz1) & HMASK;
        idx[j * 8 + 4] = (hx1 ^ hy0 ^ hz0) & HMASK;
        idx[j * 8 + 5] = (hx1 ^ hy0 ^ hz1) & HMASK;
        idx[j * 8 + 6] = (hx1 ^ hy1 ^ hz0) & HMASK;
        idx[j * 8 + 7] = (hx1 ^ hy1 ^ hz1) & HMASK;
    }

    float2 e[NB * 8];
#pragma unroll
    for (int j = 0; j < NB; ++j) {
        const float2* tab = (const float2*)tables + (size_t)(L0V + j) * TSIZE;
#pragma unroll
        for (int k = 0; k < 8; ++k)
            e[j * 8 + k] = tab[idx[j * 8 + k]];
    }
    asm volatile("" ::: "memory");   // keep loads hoisted above all consumes

#pragma unroll
    for (int j = 0; j < NB; ++j) {
        float wx = wxa[j], wy = wya[j], wz = wza[j];
        float omx = 1.0f - wx, omy = 1.0f - wy, omz = 1.0f - wz;
        const float2* ee = &e[j * 8];
        {
            float c00 = ee[0].x * omx + ee[4].x * wx;
            float c01 = ee[1].x * omx + ee[5].x * wx;
            float c10 = ee[2].x * omx + ee[6].x * wx;
            float c11 = ee[3].x * omx + ee[7].x * wx;
            float c0  = c00 * omy + c10 * wy;
            float c1  = c01 * omy + c11 * wy;
            res[2 * (L0V + j) + 0] = c0 * omz + c1 * wz;
        }
        {
            float c00 = ee[0].y * omx + ee[4].y * wx;
            float c01 = ee[1].y * omx + ee[5].y * wx;
            float c10 = ee[2].y * omx + ee[6].y * wx;
            float c11 = ee[3].y * omx + ee[7].y * wx;
            float c0  = c00 * omy + c10 * wy;
            float c1  = c01 * omy + c11 * wy;
            res[2 * (L0V + j) + 1] = c0 * omz + c1 * wz;
        }
    }
}

// ---------- fine-level body ----------

template<int L, bool DO_HIST, bool DO_MASK>
__device__ __forceinline__ void fine_body(
    const float* __restrict__ xin, const float* __restrict__ tables,
    float* __restrict__ out, unsigned* __restrict__ hist, int p)
{
#pragma clang fp contract(off)
    float x0 = xin[3 * p], x1 = xin[3 * p + 1], x2 = xin[3 * p + 2];
    float u0, u1, u2; uvw(x0, x1, x2, &u0, &u1, &u2);

    if (DO_HIST)
        atomicAdd(&hist[morton_key(u0, u1, u2)], 1u);

    const float2* tab = (const float2*)tables + (size_t)L * TSIZE;
    float r0, r1;
    level_lerp(x0, x1, x2, u0, u1, u2, NLF_TAB[L], tab, &r0, &r1);
    *(float2*)(out + (size_t)p * 32 + 2 * L) = make_float2(r0, r1);

    if (DO_MASK) {
        const float mn = -1.5f, mx = 1.5f;
        float keep = (x0 >= mn && x0 <= mx &&
                      x1 >= mn && x1 <= mx &&
                      x2 >= mn && x2 <= mx) ? 1.0f : 0.0f;
        out[(size_t)NPTS * 32 + p] = keep;
    }
}

template<int L, bool DO_HIST, bool DO_MASK>
__global__ __launch_bounds__(256)
void fine_kernel(const float* __restrict__ xin,
                 const float* __restrict__ tables,
                 float* __restrict__ out,
                 unsigned* __restrict__ hist)
{
    int p = blockIdx.x * 256 + threadIdx.x;
    if (p >= NPTS) return;
    fine_body<L, DO_HIST, DO_MASK>(xin, tables, out, hist, p);
}

// fine14 + scan: blocks 0..4095 do L14; block 4096 scans the (complete)
// histogram into cursors in-place.
__global__ __launch_bounds__(256)
void fine14_scan(const float* __restrict__ xin,
                 const float* __restrict__ tables,
                 float* __restrict__ out,
                 unsigned* __restrict__ hist)
{
    __shared__ unsigned part[256];
    if (blockIdx.x < 4096) {
        int p = blockIdx.x * 256 + threadIdx.x;
        fine_body<14, false, false>(xin, tables, out, hist, p);
        return;
    }
    int t = threadIdx.x;
    unsigned s = 0;
    for (int i = 0; i < 128; ++i) s += hist[t * 128 + i];
    part[t] = s;
    __syncthreads();
    for (int off = 1; off < 256; off <<= 1) {
        unsigned v = (t >= off) ? part[t - off] : 0;
        __syncthreads();
        part[t] += v;
        __syncthreads();
    }
    unsigned base = (t == 0) ? 0u : part[t - 1];
    for (int i = 0; i < 128; ++i) {
        unsigned c = hist[t * 128 + i];
        hist[t * 128 + i] = base;     // cursor
        base += c;
    }
}

// ---------- sort kernels ----------

// Scatter: p packed into sx4.w (bitcast) - no separate sidx buffer.
__global__ __launch_bounds__(256)
void scatter_kernel(const float* __restrict__ xin,
                    unsigned* __restrict__ cursor,
                    float4* __restrict__ sx4)
{
    int p = blockIdx.x * 256 + threadIdx.x;
    if (p >= NPTS) return;
    float x0 = xin[3 * p], x1 = xin[3 * p + 1], x2 = xin[3 * p + 2];
    float u0, u1, u2; uvw(x0, x1, x2, &u0, &u1, &u2);
    unsigned pos = atomicAdd(&cursor[morton_key(u0, u1, u2)], 1u);
    sx4[pos] = make_float4(x0, x1, x2, __uint_as_float((unsigned)p));
}

// ---------- sorted compute kernel: levels 0..9, batched (4,4,2) ----------

__global__ __launch_bounds__(256)
void coarse10_sorted(const float4* __restrict__ sx4,
                     const float* __restrict__ tables,
                     float* __restrict__ out)
{
#pragma clang fp contract(off)
    int s = blockIdx.x * 256 + threadIdx.x;
    if (s >= NPTS) return;
    float4 xv = sx4[s];
    unsigned p = __float_as_uint(xv.w);
    float u0, u1, u2; uvw(xv.x, xv.y, xv.z, &u0, &u1, &u2);

    float res[20];
    levels_batched<0, 4>(xv.x, xv.y, xv.z, u0, u1, u2, tables, res);
    levels_batched<4, 4>(xv.x, xv.y, xv.z, u0, u1, u2, tables, res);
    levels_batched<8, 2>(xv.x, xv.y, xv.z, u0, u1, u2, tables, res);

    float4* orow = (float4*)(out + (size_t)p * 32);
#pragma unroll
    for (int i = 0; i < 5; ++i)
        orow[i] = make_float4(res[4 * i + 0], res[4 * i + 1],
                              res[4 * i + 2], res[4 * i + 3]);
}

// ---------- fallback (no-workspace path) ----------

__global__ __launch_bounds__(256)
void coarse_kernel(const float* __restrict__ xin,
                   const float* __restrict__ tables,
                   float* __restrict__ out)
{
#pragma clang fp contract(off)
    int p = blockIdx.x * 256 + threadIdx.x;
    if (p >= NPTS) return;
    float x0 = xin[3 * p], x1 = xin[3 * p + 1], x2 = xin[3 * p + 2];
    float u0, u1, u2; uvw(x0, x1, x2, &u0, &u1, &u2);

    float res[16];
#pragma unroll
    for (int l = 0; l < 8; ++l) {
        const float2* tab = (const float2*)tables + (size_t)l * TSIZE;
        level_lerp(x0, x1, x2, u0, u1, u2, NLF_TAB[l], tab,
                   &res[2 * l], &res[2 * l + 1]);
    }
    float4* orow = (float4*)(out + (size_t)p * 32);
#pragma unroll
    for (int i = 0; i < 4; ++i)
        orow[i] = make_float4(res[4 * i + 0], res[4 * i + 1],
                              res[4 * i + 2], res[4 * i + 3]);
}

extern "C" void kernel_launch(void* const* d_in, const int* in_sizes, int n_in,
                              void* d_out, int out_size, void* d_ws, size_t ws_size,
                              hipStream_t stream) {
    const float* x      = (const float*)d_in[0];
    const float* tables = (const float*)d_in[2];
    float* out = (float*)d_out;

    int n = in_sizes[0] / 3;           // 1048576
    int blocks = (n + 255) / 256;      // 4096

    const size_t HIST_B  = (size_t)NBUCK * 4;               // 128 KB
    const size_t SX4_OFF = 131072;                          // aligned
    const size_t NEEDED  = SX4_OFF + (size_t)NPTS * 16;     // ≈ 16.9 MB

    if (ws_size >= NEEDED) {
        unsigned* hist = (unsigned*)d_ws;
        float4*   sx4  = (float4*)((char*)d_ws + SX4_OFF);

        hipMemsetAsync(hist, 0, HIST_B, stream);

        // One table L2-resident per launch; hist/scan ride along for free.
        fine_kernel<15, true , false><<<blocks, 256, 0, stream>>>(x, tables, out, hist);
        fine14_scan<<<blocks + 1, 256, 0, stream>>>(x, tables, out, hist);
        fine_kernel<13, false, false><<<blocks, 256, 0, stream>>>(x, tables, out, hist);
        fine_kernel<12, false, false><<<blocks, 256, 0, stream>>>(x, tables, out, hist);
        fine_kernel<11, false, false><<<blocks, 256, 0, stream>>>(x, tables, out, hist);
        fine_kernel<10, false, true ><<<blocks, 256, 0, stream>>>(x, tables, out, hist);

        scatter_kernel<<<blocks, 256, 0, stream>>>(x, hist, sx4);
        coarse10_sorted<<<blocks, 256, 0, stream>>>(sx4, tables, out);
    } else {
        coarse_kernel<<<blocks, 256, 0, stream>>>(x, tables, out);
        fine_kernel< 8, false, false><<<blocks, 256, 0, stream>>>(x, tables, out, nullptr);
        fine_kernel< 9, false, false><<<blocks, 256, 0, stream>>>(x, tables, out, nullptr);
        fine_kernel<10, false, true ><<<blocks, 256, 0, stream>>>(x, tables, out, nullptr);
        fine_kernel<11, false, false><<<blocks, 256, 0, stream>>>(x, tables, out, nullptr);
        fine_kernel<12, false, false><<<blocks, 256, 0, stream>>>(x, tables, out, nullptr);
        fine_kernel<13, false, false><<<blocks, 256, 0, stream>>>(x, tables, out, nullptr);
        fine_kernel<14, false, false><<<blocks, 256, 0, stream>>>(x, tables, out, nullptr);
        fine_kernel<15, false, false><<<blocks, 256, 0, stream>>>(x, tables, out, nullptr);
    }
}